// Round 14
// baseline (498.596 us; speedup 1.0000x reference)
//
#include <hip/hip_runtime.h>
#include <hip/hip_fp16.h>

#define D 128
#define WPITCH 136

typedef _Float16 f16x8 __attribute__((ext_vector_type(8)));
typedef float    f32x4 __attribute__((ext_vector_type(4)));
typedef int      nint2 __attribute__((ext_vector_type(2)));
typedef int      nint4 __attribute__((ext_vector_type(4)));

__device__ __forceinline__ int4 nt_load_i4(const int4* p) {
    nint4 v = __builtin_nontemporal_load(reinterpret_cast<const nint4*>(p));
    int4 o; o.x = v.x; o.y = v.y; o.z = v.z; o.w = v.w;
    return o;
}

__device__ __forceinline__ int4 pack_h8(float4 a, float4 b) {
    __half2 h0 = __floats2half2_rn(a.x, a.y);
    __half2 h1 = __floats2half2_rn(a.z, a.w);
    __half2 h2 = __floats2half2_rn(b.x, b.y);
    __half2 h3 = __floats2half2_rn(b.z, b.w);
    int4 o;
    o.x = *reinterpret_cast<int*>(&h0);
    o.y = *reinterpret_cast<int*>(&h1);
    o.z = *reinterpret_cast<int*>(&h2);
    o.w = *reinterpret_cast<int*>(&h3);
    return o;
}

// ---------------- fused conversions: x -> fp16 and 4 weight mats -> fp16 ----------------
__global__ __launch_bounds__(256) void k_cvtall(
    const float* __restrict__ x, __half* __restrict__ xh, int n8,
    const float* __restrict__ W0, const float* __restrict__ W1,
    const float* __restrict__ W2, const float* __restrict__ W3,
    _Float16* __restrict__ Wh4)
{
    const int total = n8 + 8192;
    int i = blockIdx.x * 256 + threadIdx.x;
    const int stride = gridDim.x * 256;
    for (; i < total; i += stride) {
        if (i < n8) {
            float4 a = reinterpret_cast<const float4*>(x)[(size_t)i * 2];
            float4 b = reinterpret_cast<const float4*>(x)[(size_t)i * 2 + 1];
            reinterpret_cast<int4*>(xh)[i] = pack_h8(a, b);
        } else {
            int idx = i - n8;
            int mat = idx >> 11, off = idx & 2047;
            const float* s = (mat == 0) ? W0 : (mat == 1) ? W1 : (mat == 2) ? W2 : W3;
            float4 a = reinterpret_cast<const float4*>(s)[(size_t)off * 2];
            float4 b = reinterpret_cast<const float4*>(s)[(size_t)off * 2 + 1];
            reinterpret_cast<int4*>(Wh4)[idx] = pack_h8(a, b);
        }
    }
}

// ---------------- XCD-partitioned degree histogram (int4 edge loads) ----------------
__global__ __launch_bounds__(256) void k_deg(const int* __restrict__ dst,
                                             int* __restrict__ deg, int E,
                                             int segSize, int N) {
    const int grp = blockIdx.x & 7;
    const int lo = grp * segSize;
    int hi = lo + segSize; if (hi > N) hi = N;
    const int nthr = (gridDim.x >> 3) * blockDim.x;
    const int t0 = (blockIdx.x >> 3) * blockDim.x + threadIdx.x;
    const int e4 = E >> 2;
    const int4* dst4 = reinterpret_cast<const int4*>(dst);
    for (int q = t0; q < e4; q += nthr) {
        int4 d = nt_load_i4(&dst4[q]);
        if (d.x >= lo && d.x < hi) atomicAdd(&deg[d.x], 1);
        if (d.y >= lo && d.y < hi) atomicAdd(&deg[d.y], 1);
        if (d.z >= lo && d.z < hi) atomicAdd(&deg[d.z], 1);
        if (d.w >= lo && d.w < hi) atomicAdd(&deg[d.w], 1);
    }
    for (int e = (e4 << 2) + t0; e < E; e += nthr) {
        int d = dst[e];
        if (d >= lo && d < hi) atomicAdd(&deg[d], 1);
    }
}

// ---------------- multi-block exclusive scan, phase A ----------------
__global__ __launch_bounds__(1024) void k_scan_a(const int* __restrict__ deg,
                                                 int* __restrict__ rowptr,
                                                 int* __restrict__ bsum, int N) {
    __shared__ int wsum[16];
    __shared__ int wscan[16];
    const int tid = threadIdx.x, lane = tid & 63, wid = tid >> 6;
    const int i = blockIdx.x * 4096 + tid * 4;
    int4 v = *reinterpret_cast<const int4*>(&deg[i]);
    int v0 = (i     < N) ? v.x : 0;
    int v1 = (i + 1 < N) ? v.y : 0;
    int v2 = (i + 2 < N) ? v.z : 0;
    int v3 = (i + 3 < N) ? v.w : 0;
    const int t = v0 + v1 + v2 + v3;
    int x = t;
    #pragma unroll
    for (int off = 1; off < 64; off <<= 1) {
        int u = __shfl_up(x, off);
        if (lane >= off) x += u;
    }
    if (lane == 63) wsum[wid] = x;
    __syncthreads();
    if (wid == 0) {
        int s = (lane < 16) ? wsum[lane] : 0;
        #pragma unroll
        for (int off = 1; off < 16; off <<= 1) {
            int u = __shfl_up(s, off);
            if (lane >= off) s += u;
        }
        if (lane < 16) wscan[lane] = s;
    }
    __syncthreads();
    int excl = x - t + ((wid > 0) ? wscan[wid - 1] : 0);
    if (i     < N) rowptr[i]     = excl;
    if (i + 1 < N) rowptr[i + 1] = excl + v0;
    if (i + 2 < N) rowptr[i + 2] = excl + v0 + v1;
    if (i + 3 < N) rowptr[i + 3] = excl + v0 + v1 + v2;
    if (tid == 0) bsum[blockIdx.x] = wscan[15];
}

// ---------------- scan phase B: add block offsets, seed cursor ----------------
__global__ __launch_bounds__(1024) void k_scan_b(int* __restrict__ rowptr,
                                                 int* __restrict__ cursor,
                                                 const int* __restrict__ bsum,
                                                 int N, int nb) {
    __shared__ int s_off;
    if (threadIdx.x == 0) {
        int o = 0;
        for (int b = 0; b < (int)blockIdx.x; ++b) o += bsum[b];
        s_off = o;
        if ((int)blockIdx.x == nb - 1) rowptr[N] = o + bsum[nb - 1];
    }
    __syncthreads();
    const int off = s_off;
    const int i = blockIdx.x * 4096 + threadIdx.x * 4;
    if (i + 3 < N) {
        int4 r = *reinterpret_cast<const int4*>(&rowptr[i]);
        r.x += off; r.y += off; r.z += off; r.w += off;
        *reinterpret_cast<int4*>(&rowptr[i]) = r;
        *reinterpret_cast<int4*>(&cursor[i]) = r;
    } else {
        #pragma unroll
        for (int k = 0; k < 4; ++k) {
            int ii = i + k;
            if (ii < N) {
                int r = rowptr[ii] + off;
                rowptr[ii] = r;
                cursor[ii] = r;
            }
        }
    }
}

// ---------------- XCD-partitioned CSR fill (int4 edge loads) ----------------
__global__ __launch_bounds__(256) void k_fill(const int* __restrict__ src,
                                              const int* __restrict__ dst,
                                              int* __restrict__ cursor,
                                              int* __restrict__ csr, int E,
                                              int segSize, int N) {
    const int grp = blockIdx.x & 7;
    const int lo = grp * segSize;
    int hi = lo + segSize; if (hi > N) hi = N;
    const int nthr = (gridDim.x >> 3) * blockDim.x;
    const int t0 = (blockIdx.x >> 3) * blockDim.x + threadIdx.x;
    const int e4 = E >> 2;
    const int4* dst4 = reinterpret_cast<const int4*>(dst);
    const int4* src4 = reinterpret_cast<const int4*>(src);
    for (int q = t0; q < e4; q += nthr) {
        int4 d = nt_load_i4(&dst4[q]);
        bool any = (d.x >= lo && d.x < hi) | (d.y >= lo && d.y < hi) |
                   (d.z >= lo && d.z < hi) | (d.w >= lo && d.w < hi);
        if (!any) continue;
        int4 s = nt_load_i4(&src4[q]);
        if (d.x >= lo && d.x < hi) { int p = atomicAdd(&cursor[d.x], 1); csr[p] = s.x; }
        if (d.y >= lo && d.y < hi) { int p = atomicAdd(&cursor[d.y], 1); csr[p] = s.y; }
        if (d.z >= lo && d.z < hi) { int p = atomicAdd(&cursor[d.z], 1); csr[p] = s.z; }
        if (d.w >= lo && d.w < hi) { int p = atomicAdd(&cursor[d.w], 1); csr[p] = s.w; }
    }
    for (int e = (e4 << 2) + t0; e < E; e += nthr) {
        int d = dst[e];
        if (d >= lo && d < hi) {
            int p = atomicAdd(&cursor[d], 1);
            csr[p] = src[e];
        }
    }
}

// ---------------- gather-mean aggregation (fp16 in, fp32 accum, fp16 out) ----------------
__device__ __forceinline__ void acc_add(float4& a, int2 raw) {
    __half2 h01 = *reinterpret_cast<const __half2*>(&raw.x);
    __half2 h23 = *reinterpret_cast<const __half2*>(&raw.y);
    float2 f01 = __half22float2(h01);
    float2 f23 = __half22float2(h23);
    a.x += f01.x; a.y += f01.y; a.z += f23.x; a.w += f23.y;
}

__global__ __launch_bounds__(512) void k_agg(const int* __restrict__ rowptr,
                                             const int* __restrict__ csr,
                                             const __half* __restrict__ xh,
                                             __half* __restrict__ agg, int N) {
    int w = (int)((blockIdx.x * 512u + threadIdx.x) >> 6);
    int lane = threadIdx.x & 63;
    if (w >= N) return;
    int s0 = rowptr[w], s1 = rowptr[w + 1];
    const int half = lane >> 5;
    const int c4 = lane & 31;
    const int2* xh2 = reinterpret_cast<const int2*>(xh);
    float4 a0 = make_float4(0.f, 0.f, 0.f, 0.f);
    float4 a1 = make_float4(0.f, 0.f, 0.f, 0.f);
    float4 a2 = make_float4(0.f, 0.f, 0.f, 0.f);
    float4 a3 = make_float4(0.f, 0.f, 0.f, 0.f);

    for (int p = s0; p < s1; p += 64) {
        int m = s1 - p; if (m > 64) m = 64;
        int my = (p + lane < s1) ? csr[p + lane] : 0;
        int j = 0;
        for (; j + 15 < m; j += 16) {
            int r0 = __shfl(my, j +      half);
            int r1 = __shfl(my, j + 2  + half);
            int r2 = __shfl(my, j + 4  + half);
            int r3 = __shfl(my, j + 6  + half);
            int r4 = __shfl(my, j + 8  + half);
            int r5 = __shfl(my, j + 10 + half);
            int r6 = __shfl(my, j + 12 + half);
            int r7 = __shfl(my, j + 14 + half);
            int2 v0 = xh2[(size_t)r0 * 32 + c4];
            int2 v1 = xh2[(size_t)r1 * 32 + c4];
            int2 v2 = xh2[(size_t)r2 * 32 + c4];
            int2 v3 = xh2[(size_t)r3 * 32 + c4];
            int2 v4 = xh2[(size_t)r4 * 32 + c4];
            int2 v5 = xh2[(size_t)r5 * 32 + c4];
            int2 v6 = xh2[(size_t)r6 * 32 + c4];
            int2 v7 = xh2[(size_t)r7 * 32 + c4];
            acc_add(a0, v0); acc_add(a1, v1); acc_add(a2, v2); acc_add(a3, v3);
            acc_add(a0, v4); acc_add(a1, v5); acc_add(a2, v6); acc_add(a3, v7);
        }
        for (; j + 7 < m; j += 8) {
            int r0 = __shfl(my, j +     half);
            int r1 = __shfl(my, j + 2 + half);
            int r2 = __shfl(my, j + 4 + half);
            int r3 = __shfl(my, j + 6 + half);
            int2 v0 = xh2[(size_t)r0 * 32 + c4];
            int2 v1 = xh2[(size_t)r1 * 32 + c4];
            int2 v2 = xh2[(size_t)r2 * 32 + c4];
            int2 v3 = xh2[(size_t)r3 * 32 + c4];
            acc_add(a0, v0); acc_add(a1, v1); acc_add(a2, v2); acc_add(a3, v3);
        }
        for (; j + 1 < m; j += 2) {
            int r0 = __shfl(my, j + half);
            int2 v0 = xh2[(size_t)r0 * 32 + c4];
            acc_add(a0, v0);
        }
        if (j < m) {
            int r0 = __shfl(my, j);
            int2 v0 = xh2[(size_t)r0 * 32 + c4];
            if (half == 0) acc_add(a0, v0);
        }
    }

    float4 s;
    s.x = (a0.x + a1.x) + (a2.x + a3.x);
    s.y = (a0.y + a1.y) + (a2.y + a3.y);
    s.z = (a0.z + a1.z) + (a2.z + a3.z);
    s.w = (a0.w + a1.w) + (a2.w + a3.w);
    s.x += __shfl_xor(s.x, 32);
    s.y += __shfl_xor(s.y, 32);
    s.z += __shfl_xor(s.z, 32);
    s.w += __shfl_xor(s.w, 32);

    float inv = 1.0f / fmaxf((float)(s1 - s0), 1.0f);
    if (half == 0) {
        __half2 p01 = __floats2half2_rn(s.x * inv, s.y * inv);
        __half2 p23 = __floats2half2_rn(s.z * inv, s.w * inv);
        nint2 o;
        o.x = *reinterpret_cast<int*>(&p01);
        o.y = *reinterpret_cast<int*>(&p23);
        __builtin_nontemporal_store(o, reinterpret_cast<nint2*>(agg) + (size_t)w * 32 + c4);
    }
}

// ---------------- MFMA fused-layer GEMM ----------------
// out = act( A0@W0^T + A1@W1^T + bias ),  A fp16 [N][128], W fp16 [128][128].
// 256 thr = 4 waves; block tile 64 rows x 128 cols; no LDS (W L2-resident).
template <bool RELU, bool OUT_HALF>
__global__ __launch_bounds__(256) void k_mfma2(
    const _Float16* __restrict__ A0, const _Float16* __restrict__ A1,
    const _Float16* __restrict__ W0h, const _Float16* __restrict__ W1h,
    const float* __restrict__ bias,
    float* __restrict__ outF, _Float16* __restrict__ outH, int N)
{
    const int wv = threadIdx.x >> 6;
    const int l  = threadIdx.x & 63;
    const int lr = l & 15;
    const int lk = (l >> 4) * 8;
    const int m0 = blockIdx.x * 64 + wv * 16;

    int arow = m0 + lr; if (arow >= N) arow = N - 1;

    f32x4 zero = {0.f, 0.f, 0.f, 0.f};
    f32x4 acc[8];
    #pragma unroll
    for (int g = 0; g < 8; ++g) acc[g] = zero;

    #pragma unroll
    for (int mat = 0; mat < 2; ++mat) {
        const _Float16* Ap = (mat ? A1 : A0) + (size_t)arow * D + lk;
        const _Float16* Wp = (mat ? W1h : W0h) + (size_t)lr * D + lk;
        #pragma unroll
        for (int kc = 0; kc < D; kc += 32) {
            f16x8 a = *reinterpret_cast<const f16x8*>(Ap + kc);
            #pragma unroll
            for (int g = 0; g < 8; ++g) {
                f16x8 b = *reinterpret_cast<const f16x8*>(Wp + g * 16 * D + kc);
                acc[g] = __builtin_amdgcn_mfma_f32_16x16x32_f16(a, b, acc[g], 0, 0, 0);
            }
        }
    }

    float bia[8];
    #pragma unroll
    for (int g = 0; g < 8; ++g) bia[g] = bias[g * 16 + lr];

    const int rbase = m0 + (l >> 4) * 4;
    #pragma unroll
    for (int r = 0; r < 4; ++r) {
        int row = rbase + r;
        if (row < N) {
            #pragma unroll
            for (int g = 0; g < 8; ++g) {
                float v = acc[g][r] + bia[g];
                if (RELU) v = fmaxf(v, 0.0f);
                int col = g * 16 + lr;
                if (OUT_HALF) outH[(size_t)row * D + col] = (_Float16)v;
                else __builtin_nontemporal_store(v, &outF[(size_t)row * D + col]);
            }
        }
    }
}

// ---------------- MFMA dual-head GEMM: W staged as fp16 in LDS ----------------
// Two passes (Wv then Wt); A fragments converted once and held in regs.
__global__ __launch_bounds__(256) void k_head16(
    const float* __restrict__ h,
    const float* __restrict__ Wv, const float* __restrict__ bv,
    const float* __restrict__ Wt, const float* __restrict__ bt,
    float* __restrict__ xv, float* __restrict__ xt, int N)
{
    __shared__ _Float16 sW[128 * WPITCH];   // 34.8 KB

    const int tid = threadIdx.x;
    const int wv_ = tid >> 6;
    const int l  = tid & 63;
    const int lr = l & 15;
    const int lk = (l >> 4) * 8;
    const int m0 = blockIdx.x * 64 + wv_ * 16;

    int arow = m0 + lr; if (arow >= N) arow = N - 1;

    // A fragments: fp32 -> fp16 once, held in 16 VGPRs
    f16x8 af[4];
    const float* Ap = h + (size_t)arow * D + lk;
    #pragma unroll
    for (int kc4 = 0; kc4 < 4; ++kc4) {
        float4 a0 = *reinterpret_cast<const float4*>(Ap + kc4 * 32);
        float4 a1 = *reinterpret_cast<const float4*>(Ap + kc4 * 32 + 4);
        f16x8 a;
        a[0] = (_Float16)a0.x; a[1] = (_Float16)a0.y;
        a[2] = (_Float16)a0.z; a[3] = (_Float16)a0.w;
        a[4] = (_Float16)a1.x; a[5] = (_Float16)a1.y;
        a[6] = (_Float16)a1.z; a[7] = (_Float16)a1.w;
        af[kc4] = a;
    }

    f32x4 zero = {0.f, 0.f, 0.f, 0.f};
    f32x4 accv[8], acct[8];
    #pragma unroll
    for (int g = 0; g < 8; ++g) { accv[g] = zero; acct[g] = zero; }

    // ---- pass 0: Wv ----
    #pragma unroll
    for (int it = 0; it < 8; ++it) {
        int idx = it * 256 + tid;               // 2048 chunks of 8 elems
        int row = idx >> 4, kq = idx & 15;
        float4 v0 = *reinterpret_cast<const float4*>(&Wv[row * D + kq * 8]);
        float4 v1 = *reinterpret_cast<const float4*>(&Wv[row * D + kq * 8 + 4]);
        _Float16* d = &sW[row * WPITCH + kq * 8];
        d[0] = (_Float16)v0.x; d[1] = (_Float16)v0.y;
        d[2] = (_Float16)v0.z; d[3] = (_Float16)v0.w;
        d[4] = (_Float16)v1.x; d[5] = (_Float16)v1.y;
        d[6] = (_Float16)v1.z; d[7] = (_Float16)v1.w;
    }
    __syncthreads();
    #pragma unroll
    for (int kc4 = 0; kc4 < 4; ++kc4) {
        #pragma unroll
        for (int g = 0; g < 8; ++g) {
            f16x8 b = *reinterpret_cast<const f16x8*>(
                &sW[(g * 16 + lr) * WPITCH + kc4 * 32 + lk]);
            accv[g] = __builtin_amdgcn_mfma_f32_16x16x32_f16(af[kc4], b, accv[g], 0, 0, 0);
        }
    }
    __syncthreads();

    // ---- pass 1: Wt ----
    #pragma unroll
    for (int it = 0; it < 8; ++it) {
        int idx = it * 256 + tid;
        int row = idx >> 4, kq = idx & 15;
        float4 v0 = *reinterpret_cast<const float4*>(&Wt[row * D + kq * 8]);
        float4 v1 = *reinterpret_cast<const float4*>(&Wt[row * D + kq * 8 + 4]);
        _Float16* d = &sW[row * WPITCH + kq * 8];
        d[0] = (_Float16)v0.x; d[1] = (_Float16)v0.y;
        d[2] = (_Float16)v0.z; d[3] = (_Float16)v0.w;
        d[4] = (_Float16)v1.x; d[5] = (_Float16)v1.y;
        d[6] = (_Float16)v1.z; d[7] = (_Float16)v1.w;
    }
    __syncthreads();
    #pragma unroll
    for (int kc4 = 0; kc4 < 4; ++kc4) {
        #pragma unroll
        for (int g = 0; g < 8; ++g) {
            f16x8 b = *reinterpret_cast<const f16x8*>(
                &sW[(g * 16 + lr) * WPITCH + kc4 * 32 + lk]);
            acct[g] = __builtin_amdgcn_mfma_f32_16x16x32_f16(af[kc4], b, acct[g], 0, 0, 0);
        }
    }

    float bvv[8], btt[8];
    #pragma unroll
    for (int g = 0; g < 8; ++g) {
        bvv[g] = bv[g * 16 + lr];
        btt[g] = bt[g * 16 + lr];
    }

    const int rbase = m0 + (l >> 4) * 4;
    #pragma unroll
    for (int r = 0; r < 4; ++r) {
        int row = rbase + r;
        if (row < N) {
            #pragma unroll
            for (int g = 0; g < 8; ++g) {
                int col = g * 16 + lr;
                float v = fmaxf(accv[g][r] + bvv[g], 0.0f);
                float t = fmaxf(acct[g][r] + btt[g], 0.0f);
                __builtin_nontemporal_store(v, &xv[(size_t)row * D + col]);
                __builtin_nontemporal_store(t, &xt[(size_t)row * D + col]);
            }
        }
    }
}

extern "C" void kernel_launch(void* const* d_in, const int* in_sizes, int n_in,
                              void* d_out, int out_size, void* d_ws, size_t ws_size,
                              hipStream_t stream) {
    const float* x   = (const float*)d_in[0];
    const int*   ei  = (const int*)d_in[1];
    const float* Wl0 = (const float*)d_in[2];
    const float* bl0 = (const float*)d_in[3];
    const float* Wr0 = (const float*)d_in[4];
    const float* Wl1 = (const float*)d_in[5];
    const float* bl1 = (const float*)d_in[6];
    const float* Wr1 = (const float*)d_in[7];
    const float* Wv  = (const float*)d_in[8];
    const float* bv  = (const float*)d_in[9];
    const float* Wt  = (const float*)d_in[10];
    const float* bt  = (const float*)d_in[11];

    const int N = in_sizes[0] / D;       // 100000
    const int E = in_sizes[1] / 2;       // 1600000
    const int* srcv = ei;
    const int* dstv = ei + E;

    float* out = (float*)d_out;
    const size_t nd = (size_t)N * D;
    float* h   = out;                    // final output 0
    float* xvp = out + nd;               // final output 1 (x_vision)
    float* xtp = out + 2 * nd;           // final output 2 (x_text)

    const int nb      = (N + 4095) / 4096;
    const int segSize = (N + 7) / 8;     // 8 XCD-owned dst segments

    // All scratch in d_ws (observed ~600MB):
    //   ints: deg(N) rowptr(N+1) cursor(N) csr(E) bsum(nb)   ~7.6MB
    //   xh (25.6MB) | h1h (25.6MB) | aggh (25.6MB) | Wh4 (128KB)
    size_t intWords = (size_t)(3 * N + 1) + (size_t)E + (size_t)nb;
    size_t ints_pad = (intWords * sizeof(int) + 15) & ~(size_t)15;
    size_t need = ints_pad + 3 * nd * sizeof(__half) + 65536 * sizeof(_Float16);

    char* wsB = (char*)d_ws;
    bool ws_ok = (ws_size >= need);
    // Fallback (shouldn't trigger): pack scratch into out with the R10 layout.
    int* wsI = ws_ok ? (int*)wsB : (int*)xtp;
    __half* xh   = ws_ok ? (__half*)(wsB + ints_pad) : (__half*)h;
    __half* h1h  = ws_ok ? (__half*)(wsB + ints_pad + nd * sizeof(__half))
                         : (__half*)xvp;
    __half* aggh = ws_ok ? (__half*)(wsB + ints_pad + 2 * nd * sizeof(__half))
                         : (__half*)((char*)xtp + ints_pad);
    _Float16* Wh4 = ws_ok ? (_Float16*)(wsB + ints_pad + 3 * nd * sizeof(__half))
                          : (_Float16*)((char*)xvp + nd * sizeof(__half));
    _Float16* Wl0h = Wh4;
    _Float16* Wr0h = Wh4 + 16384;
    _Float16* Wl1h = Wh4 + 32768;
    _Float16* Wr1h = Wh4 + 49152;

    int* degI   = wsI;
    int* rowptr = wsI + N;
    int* cursor = wsI + 2 * N + 1;
    int* csr    = wsI + 3 * N + 1;
    int* bsum   = wsI + 3 * N + 1 + E;

    // ---- CSR build ----
    (void)hipMemsetAsync(degI, 0, (size_t)N * sizeof(int), stream);
    k_deg <<<2048, 256, 0, stream>>>(dstv, degI, E, segSize, N);
    k_scan_a<<<nb, 1024, 0, stream>>>(degI, rowptr, bsum, N);
    k_scan_b<<<nb, 1024, 0, stream>>>(rowptr, cursor, bsum, N, nb);
    k_fill<<<2048, 256, 0, stream>>>(srcv, dstv, cursor, csr, E, segSize, N);

    const int agg_blocks = (int)(((size_t)N * 64 + 511) / 512);
    const int mblocks    = (N + 63) / 64;
    const int n8         = (int)(nd / 8);

    // ---- conversions (x + all 4 layer weights, one launch) ----
    k_cvtall<<<2048, 256, 0, stream>>>(x, xh, n8, Wl0, Wr0, Wl1, Wr1, Wh4);

    // ---- layer 0: h1 = relu(agg(x)@Wl0^T + bl0 + x@Wr0^T) -> fp16 ----
    k_agg<<<agg_blocks, 512, 0, stream>>>(rowptr, csr, xh, aggh, N);
    k_mfma2<true, true><<<mblocks, 256, 0, stream>>>(
        (const _Float16*)aggh, (const _Float16*)xh, Wl0h, Wr0h, bl0,
        nullptr, (_Float16*)h1h, N);

    // ---- layer 1: h = agg(h1)@Wl1^T + bl1 + h1@Wr1^T (fp32 final) ----
    k_agg<<<agg_blocks, 512, 0, stream>>>(rowptr, csr, h1h, aggh, N);
    k_mfma2<false, false><<<mblocks, 256, 0, stream>>>(
        (const _Float16*)aggh, (const _Float16*)h1h, Wl1h, Wr1h, bl1,
        h, nullptr, N);

    // ---- heads: xv = relu(h@Wv^T+bv), xt = relu(h@Wt^T+bt) ----
    k_head16<<<mblocks, 256, 0, stream>>>(h, Wv, bv, Wt, bt, xvp, xtp, N);
}

// Round 15
// 454.299 us; speedup vs baseline: 1.0975x; 1.0975x over previous
//
#include <hip/hip_runtime.h>
#include <hip/hip_fp16.h>

#define D 128

typedef _Float16 f16x8 __attribute__((ext_vector_type(8)));
typedef float    f32x4 __attribute__((ext_vector_type(4)));
typedef int      nint2 __attribute__((ext_vector_type(2)));

// ---------------- fp32 -> fp16 cast (vectorized) ----------------
__global__ __launch_bounds__(256) void k_cvt(const float* __restrict__ in,
                                             __half* __restrict__ out, int n8) {
    int i = blockIdx.x * 256 + threadIdx.x;
    const int stride = gridDim.x * 256;
    for (; i < n8; i += stride) {
        float4 a = reinterpret_cast<const float4*>(in)[(size_t)i * 2];
        float4 b = reinterpret_cast<const float4*>(in)[(size_t)i * 2 + 1];
        __half2 h0 = __floats2half2_rn(a.x, a.y);
        __half2 h1 = __floats2half2_rn(a.z, a.w);
        __half2 h2 = __floats2half2_rn(b.x, b.y);
        __half2 h3 = __floats2half2_rn(b.z, b.w);
        int4 o;
        o.x = *reinterpret_cast<int*>(&h0);
        o.y = *reinterpret_cast<int*>(&h1);
        o.z = *reinterpret_cast<int*>(&h2);
        o.w = *reinterpret_cast<int*>(&h3);
        reinterpret_cast<int4*>(out)[i] = o;
    }
}

// ---------------- 4 weight matrices fp32 -> fp16 ----------------
__global__ __launch_bounds__(256) void k_cvtw(const float* __restrict__ W0,
                                              const float* __restrict__ W1,
                                              const float* __restrict__ W2,
                                              const float* __restrict__ W3,
                                              _Float16* __restrict__ out) {
    int idx = blockIdx.x * 256 + threadIdx.x;      // 8192 chunks of 8 elems
    if (idx >= 8192) return;
    int mat = idx >> 11;                            // 2048 chunks per matrix
    int off = idx & 2047;
    const float* s = (mat == 0) ? W0 : (mat == 1) ? W1 : (mat == 2) ? W2 : W3;
    float4 a = reinterpret_cast<const float4*>(s)[(size_t)off * 2];
    float4 b = reinterpret_cast<const float4*>(s)[(size_t)off * 2 + 1];
    __half2 h0 = __floats2half2_rn(a.x, a.y);
    __half2 h1 = __floats2half2_rn(a.z, a.w);
    __half2 h2 = __floats2half2_rn(b.x, b.y);
    __half2 h3 = __floats2half2_rn(b.z, b.w);
    int4 o;
    o.x = *reinterpret_cast<int*>(&h0);
    o.y = *reinterpret_cast<int*>(&h1);
    o.z = *reinterpret_cast<int*>(&h2);
    o.w = *reinterpret_cast<int*>(&h3);
    reinterpret_cast<int4*>(out)[idx] = o;
}

// ---------------- XCD-partitioned degree histogram ----------------
// Blocks with bid%8==k own dst segment k (bid%8 ~ XCD id under round-robin
// dispatch) -> deg lines for a segment live in ONE XCD's L2 -> no cross-XCD
// line ping-pong on the atomic scatter.
__global__ __launch_bounds__(256) void k_deg(const int* __restrict__ dst,
                                             int* __restrict__ deg, int E,
                                             int segSize, int N) {
    const int grp = blockIdx.x & 7;
    const int lo = grp * segSize;
    int hi = lo + segSize; if (hi > N) hi = N;
    const int nthr = (gridDim.x >> 3) * blockDim.x;
    const int t0 = (blockIdx.x >> 3) * blockDim.x + threadIdx.x;
    for (int e = t0; e < E; e += nthr) {
        int d = __builtin_nontemporal_load(&dst[e]);
        if (d >= lo && d < hi) atomicAdd(&deg[d], 1);
    }
}

// ---------------- multi-block exclusive scan, phase A ----------------
__global__ __launch_bounds__(1024) void k_scan_a(const int* __restrict__ deg,
                                                 int* __restrict__ rowptr,
                                                 int* __restrict__ bsum, int N) {
    __shared__ int wsum[16];
    __shared__ int wscan[16];
    const int tid = threadIdx.x, lane = tid & 63, wid = tid >> 6;
    const int i = blockIdx.x * 4096 + tid * 4;
    int4 v = *reinterpret_cast<const int4*>(&deg[i]);
    int v0 = (i     < N) ? v.x : 0;
    int v1 = (i + 1 < N) ? v.y : 0;
    int v2 = (i + 2 < N) ? v.z : 0;
    int v3 = (i + 3 < N) ? v.w : 0;
    const int t = v0 + v1 + v2 + v3;
    int x = t;
    #pragma unroll
    for (int off = 1; off < 64; off <<= 1) {
        int u = __shfl_up(x, off);
        if (lane >= off) x += u;
    }
    if (lane == 63) wsum[wid] = x;
    __syncthreads();
    if (wid == 0) {
        int s = (lane < 16) ? wsum[lane] : 0;
        #pragma unroll
        for (int off = 1; off < 16; off <<= 1) {
            int u = __shfl_up(s, off);
            if (lane >= off) s += u;
        }
        if (lane < 16) wscan[lane] = s;
    }
    __syncthreads();
    int excl = x - t + ((wid > 0) ? wscan[wid - 1] : 0);
    if (i     < N) rowptr[i]     = excl;
    if (i + 1 < N) rowptr[i + 1] = excl + v0;
    if (i + 2 < N) rowptr[i + 2] = excl + v0 + v1;
    if (i + 3 < N) rowptr[i + 3] = excl + v0 + v1 + v2;
    if (tid == 0) bsum[blockIdx.x] = wscan[15];
}

// ---------------- scan phase B: add block offsets, seed cursor ----------------
__global__ __launch_bounds__(1024) void k_scan_b(int* __restrict__ rowptr,
                                                 int* __restrict__ cursor,
                                                 const int* __restrict__ bsum,
                                                 int N, int nb) {
    __shared__ int s_off;
    if (threadIdx.x == 0) {
        int o = 0;
        for (int b = 0; b < (int)blockIdx.x; ++b) o += bsum[b];
        s_off = o;
        if ((int)blockIdx.x == nb - 1) rowptr[N] = o + bsum[nb - 1];
    }
    __syncthreads();
    const int off = s_off;
    const int i = blockIdx.x * 4096 + threadIdx.x * 4;
    if (i + 3 < N) {
        int4 r = *reinterpret_cast<const int4*>(&rowptr[i]);
        r.x += off; r.y += off; r.z += off; r.w += off;
        *reinterpret_cast<int4*>(&rowptr[i]) = r;
        *reinterpret_cast<int4*>(&cursor[i]) = r;
    } else {
        #pragma unroll
        for (int k = 0; k < 4; ++k) {
            int ii = i + k;
            if (ii < N) {
                int r = rowptr[ii] + off;
                rowptr[ii] = r;
                cursor[ii] = r;
            }
        }
    }
}

// ---------------- XCD-partitioned CSR fill ----------------
// Same ownership scheme: csr/cursor lines of segment k written only by the
// blocks (one XCD) owning that segment -> partial-line stores merge in L2.
__global__ __launch_bounds__(256) void k_fill(const int* __restrict__ src,
                                              const int* __restrict__ dst,
                                              int* __restrict__ cursor,
                                              int* __restrict__ csr, int E,
                                              int segSize, int N) {
    const int grp = blockIdx.x & 7;
    const int lo = grp * segSize;
    int hi = lo + segSize; if (hi > N) hi = N;
    const int nthr = (gridDim.x >> 3) * blockDim.x;
    const int t0 = (blockIdx.x >> 3) * blockDim.x + threadIdx.x;
    for (int e = t0; e < E; e += nthr) {
        int d = __builtin_nontemporal_load(&dst[e]);
        if (d >= lo && d < hi) {
            int p = atomicAdd(&cursor[d], 1);
            csr[p] = __builtin_nontemporal_load(&src[e]);
        }
    }
}

// ---------------- gather-mean aggregation (fp16 in, fp32 accum, fp16 out) ----------------
__device__ __forceinline__ void acc_add(float4& a, int2 raw) {
    __half2 h01 = *reinterpret_cast<const __half2*>(&raw.x);
    __half2 h23 = *reinterpret_cast<const __half2*>(&raw.y);
    float2 f01 = __half22float2(h01);
    float2 f23 = __half22float2(h23);
    a.x += f01.x; a.y += f01.y; a.z += f23.x; a.w += f23.y;
}

__global__ __launch_bounds__(512) void k_agg(const int* __restrict__ rowptr,
                                             const int* __restrict__ csr,
                                             const __half* __restrict__ xh,
                                             __half* __restrict__ agg, int N) {
    int w = (int)((blockIdx.x * 512u + threadIdx.x) >> 6);
    int lane = threadIdx.x & 63;
    if (w >= N) return;
    int s0 = rowptr[w], s1 = rowptr[w + 1];
    const int half = lane >> 5;
    const int c4 = lane & 31;                 // 8B chunk index within row
    const int2* xh2 = reinterpret_cast<const int2*>(xh);
    float4 a0 = make_float4(0.f, 0.f, 0.f, 0.f);
    float4 a1 = make_float4(0.f, 0.f, 0.f, 0.f);
    float4 a2 = make_float4(0.f, 0.f, 0.f, 0.f);
    float4 a3 = make_float4(0.f, 0.f, 0.f, 0.f);

    for (int p = s0; p < s1; p += 64) {
        int m = s1 - p; if (m > 64) m = 64;
        int my = (p + lane < s1) ? csr[p + lane] : 0;
        int j = 0;
        for (; j + 15 < m; j += 16) {
            int r0 = __shfl(my, j +      half);
            int r1 = __shfl(my, j + 2  + half);
            int r2 = __shfl(my, j + 4  + half);
            int r3 = __shfl(my, j + 6  + half);
            int r4 = __shfl(my, j + 8  + half);
            int r5 = __shfl(my, j + 10 + half);
            int r6 = __shfl(my, j + 12 + half);
            int r7 = __shfl(my, j + 14 + half);
            int2 v0 = xh2[(size_t)r0 * 32 + c4];
            int2 v1 = xh2[(size_t)r1 * 32 + c4];
            int2 v2 = xh2[(size_t)r2 * 32 + c4];
            int2 v3 = xh2[(size_t)r3 * 32 + c4];
            int2 v4 = xh2[(size_t)r4 * 32 + c4];
            int2 v5 = xh2[(size_t)r5 * 32 + c4];
            int2 v6 = xh2[(size_t)r6 * 32 + c4];
            int2 v7 = xh2[(size_t)r7 * 32 + c4];
            acc_add(a0, v0); acc_add(a1, v1); acc_add(a2, v2); acc_add(a3, v3);
            acc_add(a0, v4); acc_add(a1, v5); acc_add(a2, v6); acc_add(a3, v7);
        }
        for (; j + 7 < m; j += 8) {
            int r0 = __shfl(my, j +     half);
            int r1 = __shfl(my, j + 2 + half);
            int r2 = __shfl(my, j + 4 + half);
            int r3 = __shfl(my, j + 6 + half);
            int2 v0 = xh2[(size_t)r0 * 32 + c4];
            int2 v1 = xh2[(size_t)r1 * 32 + c4];
            int2 v2 = xh2[(size_t)r2 * 32 + c4];
            int2 v3 = xh2[(size_t)r3 * 32 + c4];
            acc_add(a0, v0); acc_add(a1, v1); acc_add(a2, v2); acc_add(a3, v3);
        }
        for (; j + 1 < m; j += 2) {
            int r0 = __shfl(my, j + half);
            int2 v0 = xh2[(size_t)r0 * 32 + c4];
            acc_add(a0, v0);
        }
        if (j < m) {
            int r0 = __shfl(my, j);
            int2 v0 = xh2[(size_t)r0 * 32 + c4];
            if (half == 0) acc_add(a0, v0);
        }
    }

    float4 s;
    s.x = (a0.x + a1.x) + (a2.x + a3.x);
    s.y = (a0.y + a1.y) + (a2.y + a3.y);
    s.z = (a0.z + a1.z) + (a2.z + a3.z);
    s.w = (a0.w + a1.w) + (a2.w + a3.w);
    s.x += __shfl_xor(s.x, 32);
    s.y += __shfl_xor(s.y, 32);
    s.z += __shfl_xor(s.z, 32);
    s.w += __shfl_xor(s.w, 32);

    float inv = 1.0f / fmaxf((float)(s1 - s0), 1.0f);
    if (half == 0) {
        __half2 p01 = __floats2half2_rn(s.x * inv, s.y * inv);
        __half2 p23 = __floats2half2_rn(s.z * inv, s.w * inv);
        nint2 o;
        o.x = *reinterpret_cast<int*>(&p01);
        o.y = *reinterpret_cast<int*>(&p23);
        __builtin_nontemporal_store(o, reinterpret_cast<nint2*>(agg) + (size_t)w * 32 + c4);
    }
}

// ---------------- MFMA fused-layer GEMM ----------------
template <bool RELU, bool OUT_HALF>
__global__ __launch_bounds__(256) void k_mfma2(
    const _Float16* __restrict__ A0, const _Float16* __restrict__ A1,
    const _Float16* __restrict__ W0h, const _Float16* __restrict__ W1h,
    const float* __restrict__ bias,
    float* __restrict__ outF, _Float16* __restrict__ outH, int N)
{
    const int wv = threadIdx.x >> 6;
    const int l  = threadIdx.x & 63;
    const int lr = l & 15;
    const int lk = (l >> 4) * 8;
    const int m0 = blockIdx.x * 64 + wv * 16;

    int arow = m0 + lr; if (arow >= N) arow = N - 1;

    f32x4 zero = {0.f, 0.f, 0.f, 0.f};
    f32x4 acc[8];
    #pragma unroll
    for (int g = 0; g < 8; ++g) acc[g] = zero;

    #pragma unroll
    for (int mat = 0; mat < 2; ++mat) {
        const _Float16* Ap = (mat ? A1 : A0) + (size_t)arow * D + lk;
        const _Float16* Wp = (mat ? W1h : W0h) + (size_t)lr * D + lk;
        #pragma unroll
        for (int kc = 0; kc < D; kc += 32) {
            f16x8 a = *reinterpret_cast<const f16x8*>(Ap + kc);
            #pragma unroll
            for (int g = 0; g < 8; ++g) {
                f16x8 b = *reinterpret_cast<const f16x8*>(Wp + g * 16 * D + kc);
                acc[g] = __builtin_amdgcn_mfma_f32_16x16x32_f16(a, b, acc[g], 0, 0, 0);
            }
        }
    }

    float bia[8];
    #pragma unroll
    for (int g = 0; g < 8; ++g) bia[g] = bias[g * 16 + lr];

    const int rbase = m0 + (l >> 4) * 4;
    #pragma unroll
    for (int r = 0; r < 4; ++r) {
        int row = rbase + r;
        if (row < N) {
            #pragma unroll
            for (int g = 0; g < 8; ++g) {
                float v = acc[g][r] + bia[g];
                if (RELU) v = fmaxf(v, 0.0f);
                int col = g * 16 + lr;
                if (OUT_HALF) outH[(size_t)row * D + col] = (_Float16)v;
                else __builtin_nontemporal_store(v, &outF[(size_t)row * D + col]);
            }
        }
    }
}

// ---------------- MFMA dual-head GEMM: W staged as fp16 in LDS ----------------
// Two passes (Wv then Wt); A fragments converted once and held in regs.
#define WPITCH 136
__global__ __launch_bounds__(256) void k_head16(
    const float* __restrict__ h,
    const float* __restrict__ Wv, const float* __restrict__ bv,
    const float* __restrict__ Wt, const float* __restrict__ bt,
    float* __restrict__ xv, float* __restrict__ xt, int N)
{
    __shared__ _Float16 sW[128 * WPITCH];   // 34.8 KB

    const int tid = threadIdx.x;
    const int wv_ = tid >> 6;
    const int l  = tid & 63;
    const int lr = l & 15;
    const int lk = (l >> 4) * 8;
    const int m0 = blockIdx.x * 64 + wv_ * 16;

    int arow = m0 + lr; if (arow >= N) arow = N - 1;

    // A fragments: fp32 -> fp16 once, held in 16 VGPRs
    f16x8 af[4];
    const float* Ap = h + (size_t)arow * D + lk;
    #pragma unroll
    for (int kc4 = 0; kc4 < 4; ++kc4) {
        float4 a0 = *reinterpret_cast<const float4*>(Ap + kc4 * 32);
        float4 a1 = *reinterpret_cast<const float4*>(Ap + kc4 * 32 + 4);
        f16x8 a;
        a[0] = (_Float16)a0.x; a[1] = (_Float16)a0.y;
        a[2] = (_Float16)a0.z; a[3] = (_Float16)a0.w;
        a[4] = (_Float16)a1.x; a[5] = (_Float16)a1.y;
        a[6] = (_Float16)a1.z; a[7] = (_Float16)a1.w;
        af[kc4] = a;
    }

    f32x4 zero = {0.f, 0.f, 0.f, 0.f};
    f32x4 accv[8], acct[8];
    #pragma unroll
    for (int g = 0; g < 8; ++g) { accv[g] = zero; acct[g] = zero; }

    // ---- pass 0: Wv ----
    #pragma unroll
    for (int it = 0; it < 8; ++it) {
        int idx = it * 256 + tid;               // 2048 chunks of 8 elems
        int row = idx >> 4, kq = idx & 15;
        float4 v0 = *reinterpret_cast<const float4*>(&Wv[row * D + kq * 8]);
        float4 v1 = *reinterpret_cast<const float4*>(&Wv[row * D + kq * 8 + 4]);
        _Float16* d = &sW[row * WPITCH + kq * 8];
        d[0] = (_Float16)v0.x; d[1] = (_Float16)v0.y;
        d[2] = (_Float16)v0.z; d[3] = (_Float16)v0.w;
        d[4] = (_Float16)v1.x; d[5] = (_Float16)v1.y;
        d[6] = (_Float16)v1.z; d[7] = (_Float16)v1.w;
    }
    __syncthreads();
    #pragma unroll
    for (int kc4 = 0; kc4 < 4; ++kc4) {
        #pragma unroll
        for (int g = 0; g < 8; ++g) {
            f16x8 b = *reinterpret_cast<const f16x8*>(
                &sW[(g * 16 + lr) * WPITCH + kc4 * 32 + lk]);
            accv[g] = __builtin_amdgcn_mfma_f32_16x16x32_f16(af[kc4], b, accv[g], 0, 0, 0);
        }
    }
    __syncthreads();

    // ---- pass 1: Wt ----
    #pragma unroll
    for (int it = 0; it < 8; ++it) {
        int idx = it * 256 + tid;
        int row = idx >> 4, kq = idx & 15;
        float4 v0 = *reinterpret_cast<const float4*>(&Wt[row * D + kq * 8]);
        float4 v1 = *reinterpret_cast<const float4*>(&Wt[row * D + kq * 8 + 4]);
        _Float16* d = &sW[row * WPITCH + kq * 8];
        d[0] = (_Float16)v0.x; d[1] = (_Float16)v0.y;
        d[2] = (_Float16)v0.z; d[3] = (_Float16)v0.w;
        d[4] = (_Float16)v1.x; d[5] = (_Float16)v1.y;
        d[6] = (_Float16)v1.z; d[7] = (_Float16)v1.w;
    }
    __syncthreads();
    #pragma unroll
    for (int kc4 = 0; kc4 < 4; ++kc4) {
        #pragma unroll
        for (int g = 0; g < 8; ++g) {
            f16x8 b = *reinterpret_cast<const f16x8*>(
                &sW[(g * 16 + lr) * WPITCH + kc4 * 32 + lk]);
            acct[g] = __builtin_amdgcn_mfma_f32_16x16x32_f16(af[kc4], b, acct[g], 0, 0, 0);
        }
    }

    float bvv[8], btt[8];
    #pragma unroll
    for (int g = 0; g < 8; ++g) {
        bvv[g] = bv[g * 16 + lr];
        btt[g] = bt[g * 16 + lr];
    }

    const int rbase = m0 + (l >> 4) * 4;
    #pragma unroll
    for (int r = 0; r < 4; ++r) {
        int row = rbase + r;
        if (row < N) {
            #pragma unroll
            for (int g = 0; g < 8; ++g) {
                int col = g * 16 + lr;
                float v = fmaxf(accv[g][r] + bvv[g], 0.0f);
                float t = fmaxf(acct[g][r] + btt[g], 0.0f);
                __builtin_nontemporal_store(v, &xv[(size_t)row * D + col]);
                __builtin_nontemporal_store(t, &xt[(size_t)row * D + col]);
            }
        }
    }
}

extern "C" void kernel_launch(void* const* d_in, const int* in_sizes, int n_in,
                              void* d_out, int out_size, void* d_ws, size_t ws_size,
                              hipStream_t stream) {
    const float* x   = (const float*)d_in[0];
    const int*   ei  = (const int*)d_in[1];
    const float* Wl0 = (const float*)d_in[2];
    const float* bl0 = (const float*)d_in[3];
    const float* Wr0 = (const float*)d_in[4];
    const float* Wl1 = (const float*)d_in[5];
    const float* bl1 = (const float*)d_in[6];
    const float* Wr1 = (const float*)d_in[7];
    const float* Wv  = (const float*)d_in[8];
    const float* bv  = (const float*)d_in[9];
    const float* Wt  = (const float*)d_in[10];
    const float* bt  = (const float*)d_in[11];

    const int N = in_sizes[0] / D;       // 100000
    const int E = in_sizes[1] / 2;       // 1600000
    const int* srcv = ei;
    const int* dstv = ei + E;

    float* out = (float*)d_out;
    const size_t nd = (size_t)N * D;
    float* h   = out;                    // final output 0
    float* xvp = out + nd;               // final output 1 (x_vision)
    float* xtp = out + 2 * nd;           // final output 2 (x_text)

    // Scratch placement with verified lifetimes (all inside out; no d_ws needed):
    //  h  region: xh (fp16, 25.6MB)          — dead before gemm1 writes h
    //  xv region: h1h (25.6MB) + Wh4 (128KB) — dead before k_head16 writes xv
    //  xt region: ints (7.6MB) + aggh (25.6) — dead before k_head16 writes xt
    __half*    xh   = (__half*)h;
    __half*    h1h  = (__half*)xvp;
    _Float16*  Wh4  = (_Float16*)((char*)xvp + nd * sizeof(__half));
    _Float16*  Wl0h = Wh4;
    _Float16*  Wr0h = Wh4 + 16384;
    _Float16*  Wl1h = Wh4 + 32768;
    _Float16*  Wr1h = Wh4 + 49152;

    const int nb      = (N + 4095) / 4096;
    const int segSize = (N + 7) / 8;     // 8 XCD-owned dst segments
    size_t intWords = (size_t)(3 * N + 1) + (size_t)E + (size_t)nb;
    size_t ints_pad = (intWords * sizeof(int) + 15) & ~(size_t)15;

    int* wsI    = (int*)xtp;
    int* degI   = wsI;
    int* rowptr = wsI + N;
    int* cursor = wsI + 2 * N + 1;
    int* csr    = wsI + 3 * N + 1;
    int* bsum   = wsI + 3 * N + 1 + E;
    __half* aggh = (__half*)((char*)xtp + ints_pad);

    // ---- CSR build ----
    (void)hipMemsetAsync(degI, 0, (size_t)N * sizeof(int), stream);
    k_deg <<<2048, 256, 0, stream>>>(dstv, degI, E, segSize, N);
    k_scan_a<<<nb, 1024, 0, stream>>>(degI, rowptr, bsum, N);
    k_scan_b<<<nb, 1024, 0, stream>>>(rowptr, cursor, bsum, N, nb);
    k_fill<<<2048, 256, 0, stream>>>(srcv, dstv, cursor, csr, E, segSize, N);

    const int agg_blocks = (int)(((size_t)N * 64 + 511) / 512);
    const int mblocks    = (N + 63) / 64;
    const int n8         = (int)(nd / 8);

    // ---- conversions ----
    k_cvt <<<2048, 256, 0, stream>>>(x, xh, n8);
    k_cvtw<<<32, 256, 0, stream>>>(Wl0, Wr0, Wl1, Wr1, Wh4);

    // ---- layer 0: h1 = relu(agg(x)@Wl0^T + bl0 + x@Wr0^T), emitted fp16 ----
    k_agg<<<agg_blocks, 512, 0, stream>>>(rowptr, csr, xh, aggh, N);
    k_mfma2<true, true><<<mblocks, 256, 0, stream>>>(
        (const _Float16*)aggh, (const _Float16*)xh, Wl0h, Wr0h, bl0,
        nullptr, (_Float16*)h1h, N);

    // ---- layer 1: h = agg(h1)@Wl1^T + bl1 + h1@Wr1^T (fp32 final) ----
    k_agg<<<agg_blocks, 512, 0, stream>>>(rowptr, csr, h1h, aggh, N);
    k_mfma2<false, false><<<mblocks, 256, 0, stream>>>(
        (const _Float16*)aggh, (const _Float16*)h1h, Wl1h, Wr1h, bl1,
        h, nullptr, N);

    // ---- heads: xv = relu(h@Wv^T+bv), xt = relu(h@Wt^T+bt) ----
    k_head16<<<mblocks, 256, 0, stream>>>(h, Wv, bv, Wt, bt, xvp, xtp, N);
}

// Round 16
// 429.525 us; speedup vs baseline: 1.1608x; 1.0577x over previous
//
#include <hip/hip_runtime.h>
#include <hip/hip_fp16.h>

#define D 128

typedef _Float16 f16x8 __attribute__((ext_vector_type(8)));
typedef float    f32x4 __attribute__((ext_vector_type(4)));
typedef int      nint2 __attribute__((ext_vector_type(2)));

// ---------------- fp32 -> fp16 cast (vectorized) ----------------
__global__ __launch_bounds__(256) void k_cvt(const float* __restrict__ in,
                                             __half* __restrict__ out, int n8) {
    int i = blockIdx.x * 256 + threadIdx.x;
    const int stride = gridDim.x * 256;
    for (; i < n8; i += stride) {
        float4 a = reinterpret_cast<const float4*>(in)[(size_t)i * 2];
        float4 b = reinterpret_cast<const float4*>(in)[(size_t)i * 2 + 1];
        __half2 h0 = __floats2half2_rn(a.x, a.y);
        __half2 h1 = __floats2half2_rn(a.z, a.w);
        __half2 h2 = __floats2half2_rn(b.x, b.y);
        __half2 h3 = __floats2half2_rn(b.z, b.w);
        int4 o;
        o.x = *reinterpret_cast<int*>(&h0);
        o.y = *reinterpret_cast<int*>(&h1);
        o.z = *reinterpret_cast<int*>(&h2);
        o.w = *reinterpret_cast<int*>(&h3);
        reinterpret_cast<int4*>(out)[i] = o;
    }
}

// ---------------- 4 weight matrices fp32 -> fp16 ----------------
__global__ __launch_bounds__(256) void k_cvtw(const float* __restrict__ W0,
                                              const float* __restrict__ W1,
                                              const float* __restrict__ W2,
                                              const float* __restrict__ W3,
                                              _Float16* __restrict__ out) {
    int idx = blockIdx.x * 256 + threadIdx.x;      // 8192 chunks of 8 elems
    if (idx >= 8192) return;
    int mat = idx >> 11;                            // 2048 chunks per matrix
    int off = idx & 2047;
    const float* s = (mat == 0) ? W0 : (mat == 1) ? W1 : (mat == 2) ? W2 : W3;
    float4 a = reinterpret_cast<const float4*>(s)[(size_t)off * 2];
    float4 b = reinterpret_cast<const float4*>(s)[(size_t)off * 2 + 1];
    __half2 h0 = __floats2half2_rn(a.x, a.y);
    __half2 h1 = __floats2half2_rn(a.z, a.w);
    __half2 h2 = __floats2half2_rn(b.x, b.y);
    __half2 h3 = __floats2half2_rn(b.z, b.w);
    int4 o;
    o.x = *reinterpret_cast<int*>(&h0);
    o.y = *reinterpret_cast<int*>(&h1);
    o.z = *reinterpret_cast<int*>(&h2);
    o.w = *reinterpret_cast<int*>(&h3);
    reinterpret_cast<int4*>(out)[idx] = o;
}

// ---------------- XCD-partitioned degree histogram ----------------
__global__ __launch_bounds__(256) void k_deg(const int* __restrict__ dst,
                                             int* __restrict__ deg, int E,
                                             int segSize, int N) {
    const int grp = blockIdx.x & 7;
    const int lo = grp * segSize;
    int hi = lo + segSize; if (hi > N) hi = N;
    const int nthr = (gridDim.x >> 3) * blockDim.x;
    const int t0 = (blockIdx.x >> 3) * blockDim.x + threadIdx.x;
    for (int e = t0; e < E; e += nthr) {
        int d = __builtin_nontemporal_load(&dst[e]);
        if (d >= lo && d < hi) atomicAdd(&deg[d], 1);
    }
}

// ---------------- multi-block exclusive scan, phase A ----------------
__global__ __launch_bounds__(1024) void k_scan_a(const int* __restrict__ deg,
                                                 int* __restrict__ rowptr,
                                                 int* __restrict__ bsum, int N) {
    __shared__ int wsum[16];
    __shared__ int wscan[16];
    const int tid = threadIdx.x, lane = tid & 63, wid = tid >> 6;
    const int i = blockIdx.x * 4096 + tid * 4;
    int4 v = *reinterpret_cast<const int4*>(&deg[i]);
    int v0 = (i     < N) ? v.x : 0;
    int v1 = (i + 1 < N) ? v.y : 0;
    int v2 = (i + 2 < N) ? v.z : 0;
    int v3 = (i + 3 < N) ? v.w : 0;
    const int t = v0 + v1 + v2 + v3;
    int x = t;
    #pragma unroll
    for (int off = 1; off < 64; off <<= 1) {
        int u = __shfl_up(x, off);
        if (lane >= off) x += u;
    }
    if (lane == 63) wsum[wid] = x;
    __syncthreads();
    if (wid == 0) {
        int s = (lane < 16) ? wsum[lane] : 0;
        #pragma unroll
        for (int off = 1; off < 16; off <<= 1) {
            int u = __shfl_up(s, off);
            if (lane >= off) s += u;
        }
        if (lane < 16) wscan[lane] = s;
    }
    __syncthreads();
    int excl = x - t + ((wid > 0) ? wscan[wid - 1] : 0);
    if (i     < N) rowptr[i]     = excl;
    if (i + 1 < N) rowptr[i + 1] = excl + v0;
    if (i + 2 < N) rowptr[i + 2] = excl + v0 + v1;
    if (i + 3 < N) rowptr[i + 3] = excl + v0 + v1 + v2;
    if (tid == 0) bsum[blockIdx.x] = wscan[15];
}

// ---------------- scan phase B: add block offsets, seed cursor ----------------
__global__ __launch_bounds__(1024) void k_scan_b(int* __restrict__ rowptr,
                                                 int* __restrict__ cursor,
                                                 const int* __restrict__ bsum,
                                                 int N, int nb) {
    __shared__ int s_off;
    if (threadIdx.x == 0) {
        int o = 0;
        for (int b = 0; b < (int)blockIdx.x; ++b) o += bsum[b];
        s_off = o;
        if ((int)blockIdx.x == nb - 1) rowptr[N] = o + bsum[nb - 1];
    }
    __syncthreads();
    const int off = s_off;
    const int i = blockIdx.x * 4096 + threadIdx.x * 4;
    if (i + 3 < N) {
        int4 r = *reinterpret_cast<const int4*>(&rowptr[i]);
        r.x += off; r.y += off; r.z += off; r.w += off;
        *reinterpret_cast<int4*>(&rowptr[i]) = r;
        *reinterpret_cast<int4*>(&cursor[i]) = r;
    } else {
        #pragma unroll
        for (int k = 0; k < 4; ++k) {
            int ii = i + k;
            if (ii < N) {
                int r = rowptr[ii] + off;
                rowptr[ii] = r;
                cursor[ii] = r;
            }
        }
    }
}

// ---------------- XCD-partitioned CSR fill ----------------
__global__ __launch_bounds__(256) void k_fill(const int* __restrict__ src,
                                              const int* __restrict__ dst,
                                              int* __restrict__ cursor,
                                              int* __restrict__ csr, int E,
                                              int segSize, int N) {
    const int grp = blockIdx.x & 7;
    const int lo = grp * segSize;
    int hi = lo + segSize; if (hi > N) hi = N;
    const int nthr = (gridDim.x >> 3) * blockDim.x;
    const int t0 = (blockIdx.x >> 3) * blockDim.x + threadIdx.x;
    for (int e = t0; e < E; e += nthr) {
        int d = __builtin_nontemporal_load(&dst[e]);
        if (d >= lo && d < hi) {
            int p = atomicAdd(&cursor[d], 1);
            csr[p] = __builtin_nontemporal_load(&src[e]);
        }
    }
}

// ---------------- gather-mean aggregation (fp16 in, fp32 accum, fp16 out) ----------------
__device__ __forceinline__ void acc_add(float4& a, int2 raw) {
    __half2 h01 = *reinterpret_cast<const __half2*>(&raw.x);
    __half2 h23 = *reinterpret_cast<const __half2*>(&raw.y);
    float2 f01 = __half22float2(h01);
    float2 f23 = __half22float2(h23);
    a.x += f01.x; a.y += f01.y; a.z += f23.x; a.w += f23.y;
}

__global__ __launch_bounds__(512) void k_agg(const int* __restrict__ rowptr,
                                             const int* __restrict__ csr,
                                             const __half* __restrict__ xh,
                                             __half* __restrict__ agg, int N) {
    int w = (int)((blockIdx.x * 512u + threadIdx.x) >> 6);
    int lane = threadIdx.x & 63;
    if (w >= N) return;
    int s0 = rowptr[w], s1 = rowptr[w + 1];
    const int half = lane >> 5;
    const int c4 = lane & 31;                 // 8B chunk index within row
    const int2* xh2 = reinterpret_cast<const int2*>(xh);
    float4 a0 = make_float4(0.f, 0.f, 0.f, 0.f);
    float4 a1 = make_float4(0.f, 0.f, 0.f, 0.f);
    float4 a2 = make_float4(0.f, 0.f, 0.f, 0.f);
    float4 a3 = make_float4(0.f, 0.f, 0.f, 0.f);

    for (int p = s0; p < s1; p += 64) {
        int m = s1 - p; if (m > 64) m = 64;
        int my = (p + lane < s1) ? csr[p + lane] : 0;
        int j = 0;
        for (; j + 15 < m; j += 16) {
            int r0 = __shfl(my, j +      half);
            int r1 = __shfl(my, j + 2  + half);
            int r2 = __shfl(my, j + 4  + half);
            int r3 = __shfl(my, j + 6  + half);
            int r4 = __shfl(my, j + 8  + half);
            int r5 = __shfl(my, j + 10 + half);
            int r6 = __shfl(my, j + 12 + half);
            int r7 = __shfl(my, j + 14 + half);
            int2 v0 = xh2[(size_t)r0 * 32 + c4];
            int2 v1 = xh2[(size_t)r1 * 32 + c4];
            int2 v2 = xh2[(size_t)r2 * 32 + c4];
            int2 v3 = xh2[(size_t)r3 * 32 + c4];
            int2 v4 = xh2[(size_t)r4 * 32 + c4];
            int2 v5 = xh2[(size_t)r5 * 32 + c4];
            int2 v6 = xh2[(size_t)r6 * 32 + c4];
            int2 v7 = xh2[(size_t)r7 * 32 + c4];
            acc_add(a0, v0); acc_add(a1, v1); acc_add(a2, v2); acc_add(a3, v3);
            acc_add(a0, v4); acc_add(a1, v5); acc_add(a2, v6); acc_add(a3, v7);
        }
        for (; j + 7 < m; j += 8) {
            int r0 = __shfl(my, j +     half);
            int r1 = __shfl(my, j + 2 + half);
            int r2 = __shfl(my, j + 4 + half);
            int r3 = __shfl(my, j + 6 + half);
            int2 v0 = xh2[(size_t)r0 * 32 + c4];
            int2 v1 = xh2[(size_t)r1 * 32 + c4];
            int2 v2 = xh2[(size_t)r2 * 32 + c4];
            int2 v3 = xh2[(size_t)r3 * 32 + c4];
            acc_add(a0, v0); acc_add(a1, v1); acc_add(a2, v2); acc_add(a3, v3);
        }
        for (; j + 1 < m; j += 2) {
            int r0 = __shfl(my, j + half);
            int2 v0 = xh2[(size_t)r0 * 32 + c4];
            acc_add(a0, v0);
        }
        if (j < m) {
            int r0 = __shfl(my, j);
            int2 v0 = xh2[(size_t)r0 * 32 + c4];
            if (half == 0) acc_add(a0, v0);
        }
    }

    float4 s;
    s.x = (a0.x + a1.x) + (a2.x + a3.x);
    s.y = (a0.y + a1.y) + (a2.y + a3.y);
    s.z = (a0.z + a1.z) + (a2.z + a3.z);
    s.w = (a0.w + a1.w) + (a2.w + a3.w);
    s.x += __shfl_xor(s.x, 32);
    s.y += __shfl_xor(s.y, 32);
    s.z += __shfl_xor(s.z, 32);
    s.w += __shfl_xor(s.w, 32);

    float inv = 1.0f / fmaxf((float)(s1 - s0), 1.0f);
    if (half == 0) {
        __half2 p01 = __floats2half2_rn(s.x * inv, s.y * inv);
        __half2 p23 = __floats2half2_rn(s.z * inv, s.w * inv);
        nint2 o;
        o.x = *reinterpret_cast<int*>(&p01);
        o.y = *reinterpret_cast<int*>(&p23);
        __builtin_nontemporal_store(o, reinterpret_cast<nint2*>(agg) + (size_t)w * 32 + c4);
    }
}

// ---------------- MFMA fused-layer GEMM (128 rows/block, 2 tiles/wave) ----------------
// out = act( A0@W0^T + A1@W1^T + bias ). Each wave computes two 16-row tiles
// (rows m0.. and m0+64..) sharing every B fragment: 2 MFMAs per B-load.
template <bool RELU, bool OUT_HALF>
__global__ __launch_bounds__(256) void k_mfma2(
    const _Float16* __restrict__ A0, const _Float16* __restrict__ A1,
    const _Float16* __restrict__ W0h, const _Float16* __restrict__ W1h,
    const float* __restrict__ bias,
    float* __restrict__ outF, _Float16* __restrict__ outH, int N)
{
    const int wv = threadIdx.x >> 6;
    const int l  = threadIdx.x & 63;
    const int lr = l & 15;
    const int lk = (l >> 4) * 8;
    const int m0 = blockIdx.x * 128 + wv * 16;     // tile A
    const int m1 = m0 + 64;                        // tile B

    int arow0 = m0 + lr; if (arow0 >= N) arow0 = N - 1;
    int arow1 = m1 + lr; if (arow1 >= N) arow1 = N - 1;

    f32x4 zero = {0.f, 0.f, 0.f, 0.f};
    f32x4 acc0[8], acc1[8];
    #pragma unroll
    for (int g = 0; g < 8; ++g) { acc0[g] = zero; acc1[g] = zero; }

    #pragma unroll
    for (int mat = 0; mat < 2; ++mat) {
        const _Float16* Abase = (mat ? A1 : A0);
        const _Float16* Ap0 = Abase + (size_t)arow0 * D + lk;
        const _Float16* Ap1 = Abase + (size_t)arow1 * D + lk;
        const _Float16* Wp  = (mat ? W1h : W0h) + (size_t)lr * D + lk;
        #pragma unroll
        for (int kc = 0; kc < D; kc += 32) {
            f16x8 a0 = *reinterpret_cast<const f16x8*>(Ap0 + kc);
            f16x8 a1 = *reinterpret_cast<const f16x8*>(Ap1 + kc);
            #pragma unroll
            for (int g = 0; g < 8; ++g) {
                f16x8 b = *reinterpret_cast<const f16x8*>(Wp + g * 16 * D + kc);
                acc0[g] = __builtin_amdgcn_mfma_f32_16x16x32_f16(a0, b, acc0[g], 0, 0, 0);
                acc1[g] = __builtin_amdgcn_mfma_f32_16x16x32_f16(a1, b, acc1[g], 0, 0, 0);
            }
        }
    }

    float bia[8];
    #pragma unroll
    for (int g = 0; g < 8; ++g) bia[g] = bias[g * 16 + lr];

    #pragma unroll
    for (int tile = 0; tile < 2; ++tile) {
        const f32x4* acc = tile ? acc1 : acc0;
        const int rbase = (tile ? m1 : m0) + (l >> 4) * 4;
        #pragma unroll
        for (int r = 0; r < 4; ++r) {
            int row = rbase + r;
            if (row < N) {
                #pragma unroll
                for (int g = 0; g < 8; ++g) {
                    float v = acc[g][r] + bia[g];
                    if (RELU) v = fmaxf(v, 0.0f);
                    int col = g * 16 + lr;
                    if (OUT_HALF) outH[(size_t)row * D + col] = (_Float16)v;
                    else __builtin_nontemporal_store(v, &outF[(size_t)row * D + col]);
                }
            }
        }
    }
}

// ---------------- MFMA dual-head GEMM (128 rows/block, W staged once) ----------------
#define WPITCH 136
__global__ __launch_bounds__(256) void k_head16(
    const float* __restrict__ h,
    const float* __restrict__ Wv, const float* __restrict__ bv,
    const float* __restrict__ Wt, const float* __restrict__ bt,
    float* __restrict__ xv, float* __restrict__ xt, int N)
{
    __shared__ _Float16 sW[128 * WPITCH];   // 34.8 KB

    const int tid = threadIdx.x;
    const int wv_ = tid >> 6;
    const int l  = tid & 63;
    const int lr = l & 15;
    const int lk = (l >> 4) * 8;
    const int m0 = blockIdx.x * 128 + wv_ * 16;    // tile A
    const int m1 = m0 + 64;                        // tile B

    int arow0 = m0 + lr; if (arow0 >= N) arow0 = N - 1;
    int arow1 = m1 + lr; if (arow1 >= N) arow1 = N - 1;

    // A fragments for both tiles: fp32 -> fp16 once, held in 32 VGPRs
    f16x8 af0[4], af1[4];
    {
        const float* Ap0 = h + (size_t)arow0 * D + lk;
        const float* Ap1 = h + (size_t)arow1 * D + lk;
        #pragma unroll
        for (int kc4 = 0; kc4 < 4; ++kc4) {
            float4 a0 = *reinterpret_cast<const float4*>(Ap0 + kc4 * 32);
            float4 a1 = *reinterpret_cast<const float4*>(Ap0 + kc4 * 32 + 4);
            f16x8 a;
            a[0] = (_Float16)a0.x; a[1] = (_Float16)a0.y;
            a[2] = (_Float16)a0.z; a[3] = (_Float16)a0.w;
            a[4] = (_Float16)a1.x; a[5] = (_Float16)a1.y;
            a[6] = (_Float16)a1.z; a[7] = (_Float16)a1.w;
            af0[kc4] = a;
            float4 b0 = *reinterpret_cast<const float4*>(Ap1 + kc4 * 32);
            float4 b1 = *reinterpret_cast<const float4*>(Ap1 + kc4 * 32 + 4);
            f16x8 c;
            c[0] = (_Float16)b0.x; c[1] = (_Float16)b0.y;
            c[2] = (_Float16)b0.z; c[3] = (_Float16)b0.w;
            c[4] = (_Float16)b1.x; c[5] = (_Float16)b1.y;
            c[6] = (_Float16)b1.z; c[7] = (_Float16)b1.w;
            af1[kc4] = c;
        }
    }

    f32x4 zero = {0.f, 0.f, 0.f, 0.f};
    f32x4 acc0[8], acc1[8];

    // ---- pass 0: Wv ----
    #pragma unroll
    for (int it = 0; it < 8; ++it) {
        int idx = it * 256 + tid;               // 2048 chunks of 8 elems
        int row = idx >> 4, kq = idx & 15;
        float4 v0 = *reinterpret_cast<const float4*>(&Wv[row * D + kq * 8]);
        float4 v1 = *reinterpret_cast<const float4*>(&Wv[row * D + kq * 8 + 4]);
        _Float16* d = &sW[row * WPITCH + kq * 8];
        d[0] = (_Float16)v0.x; d[1] = (_Float16)v0.y;
        d[2] = (_Float16)v0.z; d[3] = (_Float16)v0.w;
        d[4] = (_Float16)v1.x; d[5] = (_Float16)v1.y;
        d[6] = (_Float16)v1.z; d[7] = (_Float16)v1.w;
    }
    __syncthreads();
    #pragma unroll
    for (int g = 0; g < 8; ++g) { acc0[g] = zero; acc1[g] = zero; }
    #pragma unroll
    for (int kc4 = 0; kc4 < 4; ++kc4) {
        #pragma unroll
        for (int g = 0; g < 8; ++g) {
            f16x8 b = *reinterpret_cast<const f16x8*>(
                &sW[(g * 16 + lr) * WPITCH + kc4 * 32 + lk]);
            acc0[g] = __builtin_amdgcn_mfma_f32_16x16x32_f16(af0[kc4], b, acc0[g], 0, 0, 0);
            acc1[g] = __builtin_amdgcn_mfma_f32_16x16x32_f16(af1[kc4], b, acc1[g], 0, 0, 0);
        }
    }
    {
        float bvv[8];
        #pragma unroll
        for (int g = 0; g < 8; ++g) bvv[g] = bv[g * 16 + lr];
        #pragma unroll
        for (int tile = 0; tile < 2; ++tile) {
            const f32x4* acc = tile ? acc1 : acc0;
            const int rbase = (tile ? m1 : m0) + (l >> 4) * 4;
            #pragma unroll
            for (int r = 0; r < 4; ++r) {
                int row = rbase + r;
                if (row < N) {
                    #pragma unroll
                    for (int g = 0; g < 8; ++g) {
                        float v = fmaxf(acc[g][r] + bvv[g], 0.0f);
                        __builtin_nontemporal_store(
                            v, &xv[(size_t)row * D + g * 16 + lr]);
                    }
                }
            }
        }
    }
    __syncthreads();

    // ---- pass 1: Wt ----
    #pragma unroll
    for (int it = 0; it < 8; ++it) {
        int idx = it * 256 + tid;
        int row = idx >> 4, kq = idx & 15;
        float4 v0 = *reinterpret_cast<const float4*>(&Wt[row * D + kq * 8]);
        float4 v1 = *reinterpret_cast<const float4*>(&Wt[row * D + kq * 8 + 4]);
        _Float16* d = &sW[row * WPITCH + kq * 8];
        d[0] = (_Float16)v0.x; d[1] = (_Float16)v0.y;
        d[2] = (_Float16)v0.z; d[3] = (_Float16)v0.w;
        d[4] = (_Float16)v1.x; d[5] = (_Float16)v1.y;
        d[6] = (_Float16)v1.z; d[7] = (_Float16)v1.w;
    }
    __syncthreads();
    #pragma unroll
    for (int g = 0; g < 8; ++g) { acc0[g] = zero; acc1[g] = zero; }
    #pragma unroll
    for (int kc4 = 0; kc4 < 4; ++kc4) {
        #pragma unroll
        for (int g = 0; g < 8; ++g) {
            f16x8 b = *reinterpret_cast<const f16x8*>(
                &sW[(g * 16 + lr) * WPITCH + kc4 * 32 + lk]);
            acc0[g] = __builtin_amdgcn_mfma_f32_16x16x32_f16(af0[kc4], b, acc0[g], 0, 0, 0);
            acc1[g] = __builtin_amdgcn_mfma_f32_16x16x32_f16(af1[kc4], b, acc1[g], 0, 0, 0);
        }
    }
    {
        float btt[8];
        #pragma unroll
        for (int g = 0; g < 8; ++g) btt[g] = bt[g * 16 + lr];
        #pragma unroll
        for (int tile = 0; tile < 2; ++tile) {
            const f32x4* acc = tile ? acc1 : acc0;
            const int rbase = (tile ? m1 : m0) + (l >> 4) * 4;
            #pragma unroll
            for (int r = 0; r < 4; ++r) {
                int row = rbase + r;
                if (row < N) {
                    #pragma unroll
                    for (int g = 0; g < 8; ++g) {
                        float t = fmaxf(acc[g][r] + btt[g], 0.0f);
                        __builtin_nontemporal_store(
                            t, &xt[(size_t)row * D + g * 16 + lr]);
                    }
                }
            }
        }
    }
}

extern "C" void kernel_launch(void* const* d_in, const int* in_sizes, int n_in,
                              void* d_out, int out_size, void* d_ws, size_t ws_size,
                              hipStream_t stream) {
    const float* x   = (const float*)d_in[0];
    const int*   ei  = (const int*)d_in[1];
    const float* Wl0 = (const float*)d_in[2];
    const float* bl0 = (const float*)d_in[3];
    const float* Wr0 = (const float*)d_in[4];
    const float* Wl1 = (const float*)d_in[5];
    const float* bl1 = (const float*)d_in[6];
    const float* Wr1 = (const float*)d_in[7];
    const float* Wv  = (const float*)d_in[8];
    const float* bv  = (const float*)d_in[9];
    const float* Wt  = (const float*)d_in[10];
    const float* bt  = (const float*)d_in[11];

    const int N = in_sizes[0] / D;       // 100000
    const int E = in_sizes[1] / 2;       // 1600000
    const int* srcv = ei;
    const int* dstv = ei + E;

    float* out = (float*)d_out;
    const size_t nd = (size_t)N * D;
    float* h   = out;                    // final output 0
    float* xvp = out + nd;               // final output 1 (x_vision)
    float* xtp = out + 2 * nd;           // final output 2 (x_text)

    // Scratch placement with verified lifetimes (all inside out; no d_ws needed):
    //  h  region: xh (fp16, 25.6MB)          — dead before gemm1 writes h
    //  xv region: h1h (25.6MB) + Wh4 (128KB) — dead before k_head16 writes xv
    //  xt region: ints (7.6MB) + aggh (25.6) — dead before k_head16 writes xt
    __half*    xh   = (__half*)h;
    __half*    h1h  = (__half*)xvp;
    _Float16*  Wh4  = (_Float16*)((char*)xvp + nd * sizeof(__half));
    _Float16*  Wl0h = Wh4;
    _Float16*  Wr0h = Wh4 + 16384;
    _Float16*  Wl1h = Wh4 + 32768;
    _Float16*  Wr1h = Wh4 + 49152;

    const int nb      = (N + 4095) / 4096;
    const int segSize = (N + 7) / 8;     // 8 XCD-owned dst segments
    size_t intWords = (size_t)(3 * N + 1) + (size_t)E + (size_t)nb;
    size_t ints_pad = (intWords * sizeof(int) + 15) & ~(size_t)15;

    int* wsI    = (int*)xtp;
    int* degI   = wsI;
    int* rowptr = wsI + N;
    int* cursor = wsI + 2 * N + 1;
    int* csr    = wsI + 3 * N + 1;
    int* bsum   = wsI + 3 * N + 1 + E;
    __half* aggh = (__half*)((char*)xtp + ints_pad);

    // ---- CSR build ----
    (void)hipMemsetAsync(degI, 0, (size_t)N * sizeof(int), stream);
    k_deg <<<2048, 256, 0, stream>>>(dstv, degI, E, segSize, N);
    k_scan_a<<<nb, 1024, 0, stream>>>(degI, rowptr, bsum, N);
    k_scan_b<<<nb, 1024, 0, stream>>>(rowptr, cursor, bsum, N, nb);
    k_fill<<<2048, 256, 0, stream>>>(srcv, dstv, cursor, csr, E, segSize, N);

    const int agg_blocks = (int)(((size_t)N * 64 + 511) / 512);
    const int mblocks    = (N + 127) / 128;
    const int n8         = (int)(nd / 8);

    // ---- conversions ----
    k_cvt <<<2048, 256, 0, stream>>>(x, xh, n8);
    k_cvtw<<<32, 256, 0, stream>>>(Wl0, Wr0, Wl1, Wr1, Wh4);

    // ---- layer 0: h1 = relu(agg(x)@Wl0^T + bl0 + x@Wr0^T), emitted fp16 ----
    k_agg<<<agg_blocks, 512, 0, stream>>>(rowptr, csr, xh, aggh, N);
    k_mfma2<true, true><<<mblocks, 256, 0, stream>>>(
        (const _Float16*)aggh, (const _Float16*)xh, Wl0h, Wr0h, bl0,
        nullptr, (_Float16*)h1h, N);

    // ---- layer 1: h = agg(h1)@Wl1^T + bl1 + h1@Wr1^T (fp32 final) ----
    k_agg<<<agg_blocks, 512, 0, stream>>>(rowptr, csr, h1h, aggh, N);
    k_mfma2<false, false><<<mblocks, 256, 0, stream>>>(
        (const _Float16*)aggh, (const _Float16*)h1h, Wl1h, Wr1h, bl1,
        h, nullptr, N);

    // ---- heads: xv = relu(h@Wv^T+bv), xt = relu(h@Wt^T+bt) ----
    k_head16<<<mblocks, 256, 0, stream>>>(h, Wv, bv, Wt, bt, xvp, xtp, N);
}